// Round 1
// baseline (934.850 us; speedup 1.0000x reference)
//
#include <hip/hip_runtime.h>
#include <math.h>

// Problem constants (from reference)
#define BB 4
#define NN 1000
#define TT 12
#define DD 64
#define HIDN 128
#define EFN 64
#define EE 64000
#define BN (BB*NN)        // 4000 segments
#define ROWS (BN*TT)      // 48000 node-time rows
#define TD (TT*DD)        // 768 elements per edge/node row-block
#define STEPF 0.1f

// ---------------------------------------------------------------------------
// CSR build helpers
// ---------------------------------------------------------------------------
__global__ __launch_bounds__(256) void k_zero(int* __restrict__ p, int n) {
    int i = blockIdx.x * 256 + threadIdx.x;
    if (i < n) p[i] = 0;
}

__global__ __launch_bounds__(256) void k_count(const int* __restrict__ bi,
                                               const int* __restrict__ si,
                                               const int* __restrict__ ri,
                                               int* __restrict__ cnt_s,
                                               int* __restrict__ cnt_r) {
    int e = blockIdx.x * 256 + threadIdx.x;
    if (e < EE) {
        int b = bi[e];
        atomicAdd(&cnt_s[b * NN + si[e]], 1);
        atomicAdd(&cnt_r[b * NN + ri[e]], 1);
    }
}

// grid=2: block 0 scans sender counts, block 1 scans receiver counts
__global__ __launch_bounds__(256) void k_scan(const int* __restrict__ cnt_s,
                                              const int* __restrict__ cnt_r,
                                              int* __restrict__ rp_s, int* __restrict__ rp_r,
                                              int* __restrict__ cur_s, int* __restrict__ cur_r) {
    const int* cnt = blockIdx.x ? cnt_r : cnt_s;
    int* rp  = blockIdx.x ? rp_r  : rp_s;
    int* cur = blockIdx.x ? cur_r : cur_s;
    __shared__ int part[256];
    int tid = threadIdx.x;
    const int chunk = 16;                       // 256*16 = 4096 >= 4000
    int bgn = tid * chunk;
    int end = min(bgn + chunk, BN);
    int s = 0;
    for (int i = bgn; i < end; ++i) s += cnt[i];
    part[tid] = s;
    __syncthreads();
    for (int off = 1; off < 256; off <<= 1) {   // inclusive Hillis-Steele
        int v = part[tid];
        if (tid >= off) v += part[tid - off];
        __syncthreads();
        part[tid] = v;
        __syncthreads();
    }
    int run = tid ? part[tid - 1] : 0;
    for (int i = bgn; i < end; ++i) { rp[i] = run; cur[i] = run; run += cnt[i]; }
    if (tid == 255) rp[BN] = part[255];
}

__global__ __launch_bounds__(256) void k_fill(const int* __restrict__ bi,
                                              const int* __restrict__ si,
                                              const int* __restrict__ ri,
                                              int* __restrict__ cur_s, int* __restrict__ cur_r,
                                              int* __restrict__ el_s, int* __restrict__ el_r) {
    int e = blockIdx.x * 256 + threadIdx.x;
    if (e < EE) {
        int b = bi[e];
        int ps = atomicAdd(&cur_s[b * NN + si[e]], 1);
        el_s[ps] = e;
        int pr = atomicAdd(&cur_r[b * NN + ri[e]], 1);
        el_r[pr] = e;
    }
}

// ---------------------------------------------------------------------------
// K1: node projections  Q1 = x@A1_w + A1_b,  Q2 = x@A2_w + A2_b
//     x rows [ROWS, 64] -> Q [ROWS, 128]. 16 rows per workgroup.
// ---------------------------------------------------------------------------
__global__ __launch_bounds__(256) void k_node_proj(const float* __restrict__ x,
                                                   const float* __restrict__ A1_w,
                                                   const float* __restrict__ A1_b,
                                                   const float* __restrict__ A2_w,
                                                   const float* __restrict__ A2_b,
                                                   float* __restrict__ Q1,
                                                   float* __restrict__ Q2) {
    __shared__ float xs[16][64];
    int tid = threadIdx.x;
    int row0 = blockIdx.x * 16;
    {   // cooperative float4 load of the 16x64 x tile
        int i = tid * 4;              // 0..1023
        int r = i >> 6, k = i & 63;
        *(float4*)&xs[r][k] = *(const float4*)&x[(size_t)(row0 + r) * 64 + k];
    }
    __syncthreads();
    int h = tid & 127;                // output column
    int w = tid >> 7;                 // 0 -> A1, 1 -> A2
    const float* W = w ? A2_w : A1_w;
    float bias = w ? A2_b[h] : A1_b[h];
    float acc[16];
#pragma unroll
    for (int r = 0; r < 16; ++r) acc[r] = 0.f;
    for (int k = 0; k < 64; ++k) {
        float wv = W[k * 128 + h];    // coalesced, L1/L2-hot (weights tiny)
#pragma unroll
        for (int r = 0; r < 16; ++r) acc[r] += xs[r][k] * wv;  // xs broadcast per wave
    }
    float* Qo = w ? Q2 : Q1;
    for (int r = 0; r < 16; ++r) Qo[(size_t)(row0 + r) * 128 + h] = acc[r] + bias;
}

// ---------------------------------------------------------------------------
// K2: per-edge v_pre = relu( (relu(Q1[s]+Q2[r]) - relu(Q1[r]+Q2[s])) @ A3 ) @ A4 + b4
//     (A3_b cancels in z_ij - z_ji). 4 edges per workgroup, 256 threads.
//     Writes v_pre into d_out's v_ij region (later normalized in-place).
// ---------------------------------------------------------------------------
__global__ __launch_bounds__(256) void k_edge(const float* __restrict__ Q1,
                                              const float* __restrict__ Q2,
                                              const int* __restrict__ bi,
                                              const int* __restrict__ si,
                                              const int* __restrict__ ri,
                                              const float* __restrict__ A3_w,
                                              const float* __restrict__ A4_w,
                                              const float* __restrict__ A4_b,
                                              float* __restrict__ vpre) {
    __shared__ float G[4][12][132];   // pitch 132 floats (528 B, 16B-aligned)
    __shared__ float Vin[4][12][64];
    __shared__ int sn[4], rn[4];
    int tid = threadIdx.x;
    int e0 = blockIdx.x * 4;
    if (tid < 4) {
        int e = e0 + tid;
        int b = bi[e];
        sn[tid] = b * NN + si[e];
        rn[tid] = b * NN + ri[e];
    }
    __syncthreads();
    // Build G = relu(Q1s + Q2r) - relu(Q1r + Q2s) for 4 edges
    for (int el = 0; el < 4; ++el) {
        int s_base = sn[el] * (TT * HIDN);
        int r_base = rn[el] * (TT * HIDN);
#pragma unroll
        for (int jj = 0; jj < 6; ++jj) {
            int idx = tid + jj * 256;         // 0..1535
            int t = idx >> 7, k = idx & 127;
            float a = Q1[s_base + idx] + Q2[r_base + idx];
            float c = Q1[r_base + idx] + Q2[s_base + idx];
            G[el][t][k] = fmaxf(a, 0.f) - fmaxf(c, 0.f);
        }
    }
    __syncthreads();
    // Stage A3: Zd = G @ A3 (K=128), Vin = relu(Zd)
    {
        int f = tid & 63;
        int el = tid >> 6;
        float acc[12];
#pragma unroll
        for (int t = 0; t < 12; ++t) acc[t] = 0.f;
        for (int kk = 0; kk < 128; kk += 4) {
            float a0 = A3_w[(kk + 0) * 64 + f];
            float a1 = A3_w[(kk + 1) * 64 + f];
            float a2 = A3_w[(kk + 2) * 64 + f];
            float a3 = A3_w[(kk + 3) * 64 + f];
#pragma unroll
            for (int t = 0; t < 12; ++t) {
                float4 g = *(const float4*)&G[el][t][kk];   // wave-broadcast LDS read
                acc[t] += g.x * a0 + g.y * a1 + g.z * a2 + g.w * a3;
            }
        }
#pragma unroll
        for (int t = 0; t < 12; ++t) Vin[el][t][f] = fmaxf(acc[t], 0.f);
    }
    __syncthreads();
    // Stage A4: v_pre = Vin @ A4 + b4 (K=64)
    {
        int d = tid & 63;
        int el = tid >> 6;
        float acc[12];
#pragma unroll
        for (int t = 0; t < 12; ++t) acc[t] = 0.f;
        for (int ff = 0; ff < 64; ff += 4) {
            float a0 = A4_w[(ff + 0) * 64 + d];
            float a1 = A4_w[(ff + 1) * 64 + d];
            float a2 = A4_w[(ff + 2) * 64 + d];
            float a3 = A4_w[(ff + 3) * 64 + d];
#pragma unroll
            for (int t = 0; t < 12; ++t) {
                float4 vv = *(const float4*)&Vin[el][t][ff];
                acc[t] += vv.x * a0 + vv.y * a1 + vv.z * a2 + vv.w * a3;
            }
        }
        float b4 = A4_b[d];
        size_t base = (size_t)(e0 + el) * TD;
#pragma unroll
        for (int t = 0; t < 12; ++t) vpre[base + t * 64 + d] = acc[t] + b4;
    }
}

// ---------------------------------------------------------------------------
// K3: segment softmax over sender segments, in-place on v (d_out v_ij region).
//     One workgroup per segment; rows of distinct segments are disjoint.
// ---------------------------------------------------------------------------
__global__ __launch_bounds__(256) void k_softmax(const int* __restrict__ rp_s,
                                                 const int* __restrict__ el_s,
                                                 float* __restrict__ v) {
    int seg = blockIdx.x;
    int beg = rp_s[seg], end = rp_s[seg + 1];
    if (beg >= end) return;
    int tid = threadIdx.x;
    for (int j = tid; j < TD; j += 256) {
        float m = -1e30f;
        for (int i = beg; i < end; ++i) {
            int e = el_s[i];
            m = fmaxf(m, v[(size_t)e * TD + j]);
        }
        float s = 0.f;
        for (int i = beg; i < end; ++i) {
            int e = el_s[i];
            s += __expf(v[(size_t)e * TD + j] - m);
        }
        float inv = 1.f / (s + 1e-12f);
        for (int i = beg; i < end; ++i) {
            int e = el_s[i];
            size_t a = (size_t)e * TD + j;
            v[a] = __expf(v[a] - m) * inv;
        }
    }
}

// ---------------------------------------------------------------------------
// K4: per-node inbound aggregation + state update.
//     One workgroup per (b,n) node; receiver CSR; writes x_updated.
// ---------------------------------------------------------------------------
__global__ __launch_bounds__(256) void k_aggregate(const int* __restrict__ rp_r,
                                                   const int* __restrict__ el_r,
                                                   const int* __restrict__ si,
                                                   const float* __restrict__ x,
                                                   const float* __restrict__ v,
                                                   float* __restrict__ xout) {
    int node = blockIdx.x;            // b*N + n
    int beg = rp_r[node], end = rp_r[node + 1];
    int tid = threadIdx.x;
    int b = node / NN;
    __shared__ int e_l[256];
    __shared__ int sb_l[256];
    float acc[3] = {0.f, 0.f, 0.f};
    for (int c = beg; c < end; c += 256) {    // chunked: safe for any segment size
        int cnt = min(end - c, 256);
        if (tid < cnt) {
            int e = el_r[c + tid];
            e_l[tid] = e;
            sb_l[tid] = (b * NN + si[e]) * TD;
        }
        __syncthreads();
        for (int i = 0; i < cnt; ++i) {
            size_t vb = (size_t)e_l[i] * TD;
            int sb = sb_l[i];
#pragma unroll
            for (int jj = 0; jj < 3; ++jj) {
                int j = tid + jj * 256;
                acc[jj] += v[vb + j] * x[sb + j];
            }
        }
        __syncthreads();
    }
    size_t nb = (size_t)node * TD;
#pragma unroll
    for (int jj = 0; jj < 3; ++jj) {
        int j = tid + jj * 256;
        float xv = x[nb + j];
        xout[nb + j] = xv + STEPF * (acc[jj] - xv);
    }
}

// ---------------------------------------------------------------------------
extern "C" void kernel_launch(void* const* d_in, const int* in_sizes, int n_in,
                              void* d_out, int out_size, void* d_ws, size_t ws_size,
                              hipStream_t stream) {
    const float* x    = (const float*)d_in[0];
    const int*   bi   = (const int*)d_in[1];
    const int*   si   = (const int*)d_in[2];
    const int*   ri   = (const int*)d_in[3];
    const float* A1_w = (const float*)d_in[4];
    const float* A1_b = (const float*)d_in[5];
    const float* A2_w = (const float*)d_in[6];
    const float* A2_b = (const float*)d_in[7];
    const float* A3_w = (const float*)d_in[8];
    // d_in[9] = A3_b: cancels in z_ij - z_ji, unused
    const float* A4_w = (const float*)d_in[10];
    const float* A4_b = (const float*)d_in[11];

    float* xout = (float*)d_out;                          // [B,N,T,D]
    float* v    = (float*)d_out + (size_t)BN * TD;        // [E,T,D]: v_pre then v_ij in-place

    // Workspace layout: Q1, Q2 (fp32), then CSR ints (~49.8 MB total)
    float* Q1 = (float*)d_ws;
    float* Q2 = Q1 + (size_t)ROWS * HIDN;
    int* cnt_s = (int*)(Q2 + (size_t)ROWS * HIDN);
    int* cnt_r = cnt_s + BN;
    int* rp_s  = cnt_r + BN;
    int* rp_r  = rp_s + BN + 1;
    int* cur_s = rp_r + BN + 1;
    int* cur_r = cur_s + BN;
    int* el_s  = cur_r + BN;
    int* el_r  = el_s + EE;

    k_zero<<<(2 * BN + 255) / 256, 256, 0, stream>>>(cnt_s, 2 * BN);
    k_count<<<EE / 256, 256, 0, stream>>>(bi, si, ri, cnt_s, cnt_r);
    k_scan<<<2, 256, 0, stream>>>(cnt_s, cnt_r, rp_s, rp_r, cur_s, cur_r);
    k_fill<<<EE / 256, 256, 0, stream>>>(bi, si, ri, cur_s, cur_r, el_s, el_r);
    k_node_proj<<<ROWS / 16, 256, 0, stream>>>(x, A1_w, A1_b, A2_w, A2_b, Q1, Q2);
    k_edge<<<EE / 4, 256, 0, stream>>>(Q1, Q2, bi, si, ri, A3_w, A4_w, A4_b, v);
    k_softmax<<<BN, 256, 0, stream>>>(rp_s, el_s, v);
    k_aggregate<<<BN, 256, 0, stream>>>(rp_r, el_r, si, x, v, xout);
}

// Round 2
// 563.534 us; speedup vs baseline: 1.6589x; 1.6589x over previous
//
#include <hip/hip_runtime.h>
#include <math.h>

// Problem constants (from reference)
#define BB 4
#define NN 1000
#define TT 12
#define DD 64
#define HIDN 128
#define EFN 64
#define EE 64000
#define BN (BB*NN)        // 4000 segments
#define ROWS (BN*TT)      // 48000 node-time rows
#define TD (TT*DD)        // 768 elements per edge/node row-block
#define STEPF 0.1f

typedef __attribute__((ext_vector_type(8))) short bfrag8;          // 8 x bf16 (4 VGPR)
typedef __attribute__((ext_vector_type(8))) unsigned short u16x8;  // raw 16B load
typedef __attribute__((ext_vector_type(4))) float f32x4;           // MFMA acc

__device__ __forceinline__ float bf2f(unsigned short u) {
    union { unsigned int i; float f; } p; p.i = ((unsigned int)u) << 16; return p.f;
}
__device__ __forceinline__ unsigned short f2bf(float x) {
    union { float f; unsigned int i; } p; p.f = x;
    unsigned int r = (p.i + 0x7FFFu + ((p.i >> 16) & 1u)) >> 16;   // RNE
    return (unsigned short)r;
}

// ---------------------------------------------------------------------------
// CSR build helpers
// ---------------------------------------------------------------------------
__global__ __launch_bounds__(256) void k_zero(int* __restrict__ p, int n) {
    int i = blockIdx.x * 256 + threadIdx.x;
    if (i < n) p[i] = 0;
}

__global__ __launch_bounds__(256) void k_count(const int* __restrict__ bi,
                                               const int* __restrict__ si,
                                               const int* __restrict__ ri,
                                               int* __restrict__ cnt_s,
                                               int* __restrict__ cnt_r) {
    int e = blockIdx.x * 256 + threadIdx.x;
    if (e < EE) {
        int b = bi[e];
        atomicAdd(&cnt_s[b * NN + si[e]], 1);
        atomicAdd(&cnt_r[b * NN + ri[e]], 1);
    }
}

__global__ __launch_bounds__(256) void k_scan(const int* __restrict__ cnt_s,
                                              const int* __restrict__ cnt_r,
                                              int* __restrict__ rp_s, int* __restrict__ rp_r,
                                              int* __restrict__ cur_s, int* __restrict__ cur_r) {
    const int* cnt = blockIdx.x ? cnt_r : cnt_s;
    int* rp  = blockIdx.x ? rp_r  : rp_s;
    int* cur = blockIdx.x ? cur_r : cur_s;
    __shared__ int part[256];
    int tid = threadIdx.x;
    const int chunk = 16;
    int bgn = tid * chunk;
    int end = min(bgn + chunk, BN);
    int s = 0;
    for (int i = bgn; i < end; ++i) s += cnt[i];
    part[tid] = s;
    __syncthreads();
    for (int off = 1; off < 256; off <<= 1) {
        int v = part[tid];
        if (tid >= off) v += part[tid - off];
        __syncthreads();
        part[tid] = v;
        __syncthreads();
    }
    int run = tid ? part[tid - 1] : 0;
    for (int i = bgn; i < end; ++i) { rp[i] = run; cur[i] = run; run += cnt[i]; }
    if (tid == 255) rp[BN] = part[255];
}

__global__ __launch_bounds__(256) void k_fill(const int* __restrict__ bi,
                                              const int* __restrict__ si,
                                              const int* __restrict__ ri,
                                              int* __restrict__ cur_s, int* __restrict__ cur_r,
                                              int* __restrict__ el_s, int* __restrict__ el_r) {
    int e = blockIdx.x * 256 + threadIdx.x;
    if (e < EE) {
        int b = bi[e];
        int ps = atomicAdd(&cur_s[b * NN + si[e]], 1);
        el_s[ps] = e;
        int pr = atomicAdd(&cur_r[b * NN + ri[e]], 1);
        el_r[pr] = e;
    }
}

// ---------------------------------------------------------------------------
// Weight prep: repack A3_w [128,64] and A4_w [64,64] into bf16 MFMA B-fragment
// order for 16x16x32: frag[kt][nt][lane][j] = W[kt*32 + (lane>>4)*8 + j][nt*16 + (lane&15)]
// ---------------------------------------------------------------------------
__global__ __launch_bounds__(256) void k_prep_w(const float* __restrict__ A3_w,
                                                const float* __restrict__ A4_w,
                                                unsigned short* __restrict__ W3f,
                                                unsigned short* __restrict__ W4f) {
    int i = blockIdx.x * 256 + threadIdx.x;    // 0 .. 12287
    if (i < 8192) {                            // 4 kt * 4 nt * 64 lanes * 8 j
        int j = i & 7, lane = (i >> 3) & 63, nt = (i >> 9) & 3, kt = i >> 11;
        int k = kt * 32 + (lane >> 4) * 8 + j;
        int n = nt * 16 + (lane & 15);
        W3f[i] = f2bf(A3_w[k * 64 + n]);
    } else if (i < 12288) {                    // 2 kt * 4 nt * 64 * 8
        int ii = i - 8192;
        int j = ii & 7, lane = (ii >> 3) & 63, nt = (ii >> 9) & 3, kt = ii >> 11;
        int k = kt * 32 + (lane >> 4) * 8 + j;
        int n = nt * 16 + (lane & 15);
        W4f[ii] = f2bf(A4_w[k * 64 + n]);
    }
}

// ---------------------------------------------------------------------------
// K1: node projections Q1 = x@A1_w + A1_b, Q2 = x@A2_w + A2_b -> bf16
// ---------------------------------------------------------------------------
__global__ __launch_bounds__(256) void k_node_proj(const float* __restrict__ x,
                                                   const float* __restrict__ A1_w,
                                                   const float* __restrict__ A1_b,
                                                   const float* __restrict__ A2_w,
                                                   const float* __restrict__ A2_b,
                                                   unsigned short* __restrict__ Q1,
                                                   unsigned short* __restrict__ Q2) {
    __shared__ float xs[16][64];
    int tid = threadIdx.x;
    int row0 = blockIdx.x * 16;
    {
        int i = tid * 4;
        int r = i >> 6, k = i & 63;
        *(float4*)&xs[r][k] = *(const float4*)&x[(size_t)(row0 + r) * 64 + k];
    }
    __syncthreads();
    int h = tid & 127;
    int w = tid >> 7;
    const float* W = w ? A2_w : A1_w;
    float bias = w ? A2_b[h] : A1_b[h];
    float acc[16];
#pragma unroll
    for (int r = 0; r < 16; ++r) acc[r] = 0.f;
    for (int k = 0; k < 64; ++k) {
        float wv = W[k * 128 + h];
#pragma unroll
        for (int r = 0; r < 16; ++r) acc[r] += xs[r][k] * wv;
    }
    unsigned short* Qo = w ? Q2 : Q1;
    for (int r = 0; r < 16; ++r) Qo[(size_t)(row0 + r) * 128 + h] = f2bf(acc[r] + bias);
}

// ---------------------------------------------------------------------------
// K2 (MFMA): per-edge v_pre = relu(G @ A3) @ A4 + b4,
//            G = relu(Q1s+Q2r) - relu(Q1r+Q2s)  [12 x 128] per edge.
// One wave per edge; edges walked in sender-CSR order for Q reuse.
// A3: M=16(12) N=64 K=128 -> 16 MFMAs; A4: M=16 N=64 K=64 -> 8 MFMAs.
// Weight B-frags register-resident; relu-H round-trips per-wave LDS tile.
// ---------------------------------------------------------------------------
__global__ __launch_bounds__(256) void k_edge_mfma(const unsigned short* __restrict__ Q1,
                                                   const unsigned short* __restrict__ Q2,
                                                   const int* __restrict__ bi,
                                                   const int* __restrict__ si,
                                                   const int* __restrict__ ri,
                                                   const int* __restrict__ el_s,
                                                   const unsigned short* __restrict__ W3f,
                                                   const unsigned short* __restrict__ W4f,
                                                   const float* __restrict__ A4_b,
                                                   float* __restrict__ vpre) {
    __shared__ __align__(16) float Hs[4][16][68];   // per-wave private tile, pitch 68
    int lane = threadIdx.x & 63;
    int wv   = threadIdx.x >> 6;
    int quad = lane >> 4;
    int m    = lane & 15;
    int kbase = quad * 8;

    // Register-resident weight fragments (loaded once per wave)
    bfrag8 w3[4][4], w4[2][4];
#pragma unroll
    for (int kt = 0; kt < 4; ++kt)
#pragma unroll
        for (int nt = 0; nt < 4; ++nt)
            w3[kt][nt] = *(const bfrag8*)&W3f[((kt * 4 + nt) * 64 + lane) * 8];
#pragma unroll
    for (int kt = 0; kt < 2; ++kt)
#pragma unroll
        for (int nt = 0; nt < 4; ++nt)
            w4[kt][nt] = *(const bfrag8*)&W4f[((kt * 4 + nt) * 64 + lane) * 8];
    float b4[4];
#pragma unroll
    for (int nt = 0; nt < 4; ++nt) b4[nt] = A4_b[nt * 16 + m];

    const bfrag8 zfrag = {0, 0, 0, 0, 0, 0, 0, 0};
    int gw = blockIdx.x * 4 + wv;       // 8000 waves total
    const int EPW = 8;                  // edges per wave (consecutive CSR slots)

    for (int ii = 0; ii < EPW; ++ii) {
        int i = gw * EPW + ii;
        int e = el_s[i];
        int b = bi[e];
        int sn = b * NN + si[e];
        int rn = b * NN + ri[e];

        // Build A-fragments of G directly from gathered Q rows (t = m)
        bfrag8 af[4];
        if (m < 12) {
            const unsigned short* p1s = Q1 + (size_t)sn * (TT * HIDN) + m * 128 + kbase;
            const unsigned short* p2r = Q2 + (size_t)rn * (TT * HIDN) + m * 128 + kbase;
            const unsigned short* p1r = Q1 + (size_t)rn * (TT * HIDN) + m * 128 + kbase;
            const unsigned short* p2s = Q2 + (size_t)sn * (TT * HIDN) + m * 128 + kbase;
#pragma unroll
            for (int kt = 0; kt < 4; ++kt) {
                u16x8 x1 = *(const u16x8*)(p1s + kt * 32);
                u16x8 x2 = *(const u16x8*)(p2r + kt * 32);
                u16x8 x3 = *(const u16x8*)(p1r + kt * 32);
                u16x8 x4 = *(const u16x8*)(p2s + kt * 32);
                union { bfrag8 v; unsigned short u[8]; } fr;
#pragma unroll
                for (int j = 0; j < 8; ++j) {
                    float a = bf2f(x1[j]) + bf2f(x2[j]);
                    float c = bf2f(x3[j]) + bf2f(x4[j]);
                    fr.u[j] = f2bf(fmaxf(a, 0.f) - fmaxf(c, 0.f));
                }
                af[kt] = fr.v;
            }
        } else {
#pragma unroll
            for (int kt = 0; kt < 4; ++kt) af[kt] = zfrag;
        }

        // Stage A3: Zd = G @ A3 (K=128), 4 N-tiles x 4 K-steps
        f32x4 acc[4];
#pragma unroll
        for (int nt = 0; nt < 4; ++nt) acc[nt] = (f32x4){0.f, 0.f, 0.f, 0.f};
#pragma unroll
        for (int kt = 0; kt < 4; ++kt)
#pragma unroll
            for (int nt = 0; nt < 4; ++nt)
                acc[nt] = __builtin_amdgcn_mfma_f32_16x16x32_bf16(af[kt], w3[kt][nt], acc[nt], 0, 0, 0);

        // relu -> LDS (C/D layout in, A layout out); wave-private, no barrier
#pragma unroll
        for (int nt = 0; nt < 4; ++nt)
#pragma unroll
            for (int r = 0; r < 4; ++r)
                Hs[wv][quad * 4 + r][nt * 16 + m] = fmaxf(acc[nt][r], 0.f);

        bfrag8 hf[2];
#pragma unroll
        for (int kt = 0; kt < 2; ++kt) {
            const float* hp = &Hs[wv][m][kt * 32 + kbase];
            float4 h0 = *(const float4*)hp;
            float4 h1 = *(const float4*)(hp + 4);
            union { bfrag8 v; unsigned short u[8]; } fr;
            fr.u[0] = f2bf(h0.x); fr.u[1] = f2bf(h0.y);
            fr.u[2] = f2bf(h0.z); fr.u[3] = f2bf(h0.w);
            fr.u[4] = f2bf(h1.x); fr.u[5] = f2bf(h1.y);
            fr.u[6] = f2bf(h1.z); fr.u[7] = f2bf(h1.w);
            hf[kt] = fr.v;
        }

        // Stage A4: v_pre = H @ A4 + b4 (K=64), bias folded into C
        size_t ebase = (size_t)e * TD;
#pragma unroll
        for (int nt = 0; nt < 4; ++nt) {
            f32x4 o = (f32x4){b4[nt], b4[nt], b4[nt], b4[nt]};
#pragma unroll
            for (int kt = 0; kt < 2; ++kt)
                o = __builtin_amdgcn_mfma_f32_16x16x32_bf16(hf[kt], w4[kt][nt], o, 0, 0, 0);
            if (quad < 3) {   // rows 12..15 are padding
#pragma unroll
                for (int r = 0; r < 4; ++r) {
                    int t = quad * 4 + r;
                    vpre[ebase + t * 64 + nt * 16 + m] = o[r];
                }
            }
        }
    }
}

// ---------------------------------------------------------------------------
// K3: segment softmax over sender segments, in-place on v (d_out v_ij region).
// ---------------------------------------------------------------------------
__global__ __launch_bounds__(256) void k_softmax(const int* __restrict__ rp_s,
                                                 const int* __restrict__ el_s,
                                                 float* __restrict__ v) {
    int seg = blockIdx.x;
    int beg = rp_s[seg], end = rp_s[seg + 1];
    if (beg >= end) return;
    int tid = threadIdx.x;
    for (int j = tid; j < TD; j += 256) {
        float m = -1e30f;
        for (int i = beg; i < end; ++i) {
            int e = el_s[i];
            m = fmaxf(m, v[(size_t)e * TD + j]);
        }
        float s = 0.f;
        for (int i = beg; i < end; ++i) {
            int e = el_s[i];
            s += __expf(v[(size_t)e * TD + j] - m);
        }
        float inv = 1.f / (s + 1e-12f);
        for (int i = beg; i < end; ++i) {
            int e = el_s[i];
            size_t a = (size_t)e * TD + j;
            v[a] = __expf(v[a] - m) * inv;
        }
    }
}

// ---------------------------------------------------------------------------
// K4: per-node inbound aggregation + state update.
// ---------------------------------------------------------------------------
__global__ __launch_bounds__(256) void k_aggregate(const int* __restrict__ rp_r,
                                                   const int* __restrict__ el_r,
                                                   const int* __restrict__ si,
                                                   const float* __restrict__ x,
                                                   const float* __restrict__ v,
                                                   float* __restrict__ xout) {
    int node = blockIdx.x;
    int beg = rp_r[node], end = rp_r[node + 1];
    int tid = threadIdx.x;
    int b = node / NN;
    __shared__ int e_l[256];
    __shared__ int sb_l[256];
    float acc[3] = {0.f, 0.f, 0.f};
    for (int c = beg; c < end; c += 256) {
        int cnt = min(end - c, 256);
        if (tid < cnt) {
            int e = el_r[c + tid];
            e_l[tid] = e;
            sb_l[tid] = (b * NN + si[e]) * TD;
        }
        __syncthreads();
        for (int i = 0; i < cnt; ++i) {
            size_t vb = (size_t)e_l[i] * TD;
            int sb = sb_l[i];
#pragma unroll
            for (int jj = 0; jj < 3; ++jj) {
                int j = tid + jj * 256;
                acc[jj] += v[vb + j] * x[sb + j];
            }
        }
        __syncthreads();
    }
    size_t nb = (size_t)node * TD;
#pragma unroll
    for (int jj = 0; jj < 3; ++jj) {
        int j = tid + jj * 256;
        float xv = x[nb + j];
        xout[nb + j] = xv + STEPF * (acc[jj] - xv);
    }
}

// ---------------------------------------------------------------------------
extern "C" void kernel_launch(void* const* d_in, const int* in_sizes, int n_in,
                              void* d_out, int out_size, void* d_ws, size_t ws_size,
                              hipStream_t stream) {
    const float* x    = (const float*)d_in[0];
    const int*   bi   = (const int*)d_in[1];
    const int*   si   = (const int*)d_in[2];
    const int*   ri   = (const int*)d_in[3];
    const float* A1_w = (const float*)d_in[4];
    const float* A1_b = (const float*)d_in[5];
    const float* A2_w = (const float*)d_in[6];
    const float* A2_b = (const float*)d_in[7];
    const float* A3_w = (const float*)d_in[8];
    // d_in[9] = A3_b: cancels in z_ij - z_ji, unused
    const float* A4_w = (const float*)d_in[10];
    const float* A4_b = (const float*)d_in[11];

    float* xout = (float*)d_out;                          // [B,N,T,D]
    float* v    = (float*)d_out + (size_t)BN * TD;        // [E,T,D]: v_pre then v_ij in-place

    // Workspace: Q1,Q2 bf16; W3f/W4f frag-packed weights; CSR ints (~25 MB)
    unsigned short* Q1  = (unsigned short*)d_ws;
    unsigned short* Q2  = Q1 + (size_t)ROWS * HIDN;
    unsigned short* W3f = Q2 + (size_t)ROWS * HIDN;       // 8192
    unsigned short* W4f = W3f + 8192;                     // 4096
    int* cnt_s = (int*)(W4f + 4096);
    int* cnt_r = cnt_s + BN;
    int* rp_s  = cnt_r + BN;
    int* rp_r  = rp_s + BN + 1;
    int* cur_s = rp_r + BN + 1;
    int* cur_r = cur_s + BN;
    int* el_s  = cur_r + BN;
    int* el_r  = el_s + EE;

    k_zero<<<(2 * BN + 255) / 256, 256, 0, stream>>>(cnt_s, 2 * BN);
    k_count<<<EE / 256, 256, 0, stream>>>(bi, si, ri, cnt_s, cnt_r);
    k_scan<<<2, 256, 0, stream>>>(cnt_s, cnt_r, rp_s, rp_r, cur_s, cur_r);
    k_fill<<<EE / 256, 256, 0, stream>>>(bi, si, ri, cur_s, cur_r, el_s, el_r);
    k_prep_w<<<48, 256, 0, stream>>>(A3_w, A4_w, W3f, W4f);
    k_node_proj<<<ROWS / 16, 256, 0, stream>>>(x, A1_w, A1_b, A2_w, A2_b, Q1, Q2);
    k_edge_mfma<<<2000, 256, 0, stream>>>(Q1, Q2, bi, si, ri, el_s, W3f, W4f, A4_b, v);
    k_softmax<<<BN, 256, 0, stream>>>(rp_s, el_s, v);
    k_aggregate<<<BN, 256, 0, stream>>>(rp_r, el_r, si, x, v, xout);
}

// Round 3
// 496.346 us; speedup vs baseline: 1.8835x; 1.1354x over previous
//
#include <hip/hip_runtime.h>
#include <math.h>

// Problem constants (from reference)
#define BB 4
#define NN 1000
#define TT 12
#define DD 64
#define HIDN 128
#define EFN 64
#define EE 64000
#define BN (BB*NN)        // 4000 segments
#define ROWS (BN*TT)      // 48000 node-time rows
#define TD (TT*DD)        // 768 elements per edge/node row-block
#define STEPF 0.1f
#define MAXSEG 32         // LDS-resident edges per sender segment

typedef __attribute__((ext_vector_type(8))) short bfrag8;          // 8 x bf16 (4 VGPR)
typedef __attribute__((ext_vector_type(8))) unsigned short u16x8;  // raw 16B load
typedef __attribute__((ext_vector_type(4))) float f32x4;           // MFMA acc

__device__ __forceinline__ float bf2f(unsigned short u) {
    union { unsigned int i; float f; } p; p.i = ((unsigned int)u) << 16; return p.f;
}
__device__ __forceinline__ unsigned short f2bf(float x) {
    union { float f; unsigned int i; } p; p.f = x;
    unsigned int r = (p.i + 0x7FFFu + ((p.i >> 16) & 1u)) >> 16;   // RNE
    return (unsigned short)r;
}

// ---------------------------------------------------------------------------
// CSR build helpers
// ---------------------------------------------------------------------------
__global__ __launch_bounds__(256) void k_zero(int* __restrict__ p, int n) {
    int i = blockIdx.x * 256 + threadIdx.x;
    if (i < n) p[i] = 0;
}

__global__ __launch_bounds__(256) void k_count(const int* __restrict__ bi,
                                               const int* __restrict__ si,
                                               const int* __restrict__ ri,
                                               int* __restrict__ cnt_s,
                                               int* __restrict__ cnt_r) {
    int e = blockIdx.x * 256 + threadIdx.x;
    if (e < EE) {
        int b = bi[e];
        atomicAdd(&cnt_s[b * NN + si[e]], 1);
        atomicAdd(&cnt_r[b * NN + ri[e]], 1);
    }
}

__global__ __launch_bounds__(256) void k_scan(const int* __restrict__ cnt_s,
                                              const int* __restrict__ cnt_r,
                                              int* __restrict__ rp_s, int* __restrict__ rp_r,
                                              int* __restrict__ cur_s, int* __restrict__ cur_r) {
    const int* cnt = blockIdx.x ? cnt_r : cnt_s;
    int* rp  = blockIdx.x ? rp_r  : rp_s;
    int* cur = blockIdx.x ? cur_r : cur_s;
    __shared__ int part[256];
    int tid = threadIdx.x;
    const int chunk = 16;
    int bgn = tid * chunk;
    int end = min(bgn + chunk, BN);
    int s = 0;
    for (int i = bgn; i < end; ++i) s += cnt[i];
    part[tid] = s;
    __syncthreads();
    for (int off = 1; off < 256; off <<= 1) {
        int v = part[tid];
        if (tid >= off) v += part[tid - off];
        __syncthreads();
        part[tid] = v;
        __syncthreads();
    }
    int run = tid ? part[tid - 1] : 0;
    for (int i = bgn; i < end; ++i) { rp[i] = run; cur[i] = run; run += cnt[i]; }
    if (tid == 255) rp[BN] = part[255];
}

__global__ __launch_bounds__(256) void k_fill(const int* __restrict__ bi,
                                              const int* __restrict__ si,
                                              const int* __restrict__ ri,
                                              int* __restrict__ cur_s, int* __restrict__ cur_r,
                                              int* __restrict__ el_s, int* __restrict__ el_r) {
    int e = blockIdx.x * 256 + threadIdx.x;
    if (e < EE) {
        int b = bi[e];
        int ps = atomicAdd(&cur_s[b * NN + si[e]], 1);
        el_s[ps] = e;
        int pr = atomicAdd(&cur_r[b * NN + ri[e]], 1);
        el_r[pr] = e;
    }
}

// ---------------------------------------------------------------------------
// Weight prep: repack A3_w [128,64] and A4_w [64,64] into bf16 MFMA B-fragment
// order for 16x16x32: frag[kt][nt][lane][j] = W[kt*32 + (lane>>4)*8 + j][nt*16 + (lane&15)]
// ---------------------------------------------------------------------------
__global__ __launch_bounds__(256) void k_prep_w(const float* __restrict__ A3_w,
                                                const float* __restrict__ A4_w,
                                                unsigned short* __restrict__ W3f,
                                                unsigned short* __restrict__ W4f) {
    int i = blockIdx.x * 256 + threadIdx.x;    // 0 .. 12287
    if (i < 8192) {
        int j = i & 7, lane = (i >> 3) & 63, nt = (i >> 9) & 3, kt = i >> 11;
        int k = kt * 32 + (lane >> 4) * 8 + j;
        int n = nt * 16 + (lane & 15);
        W3f[i] = f2bf(A3_w[k * 64 + n]);
    } else if (i < 12288) {
        int ii = i - 8192;
        int j = ii & 7, lane = (ii >> 3) & 63, nt = (ii >> 9) & 3, kt = ii >> 11;
        int k = kt * 32 + (lane >> 4) * 8 + j;
        int n = nt * 16 + (lane & 15);
        W4f[ii] = f2bf(A4_w[k * 64 + n]);
    }
}

// ---------------------------------------------------------------------------
// K1: node projections Q1 = x@A1_w + A1_b, Q2 = x@A2_w + A2_b -> bf16
// ---------------------------------------------------------------------------
__global__ __launch_bounds__(256) void k_node_proj(const float* __restrict__ x,
                                                   const float* __restrict__ A1_w,
                                                   const float* __restrict__ A1_b,
                                                   const float* __restrict__ A2_w,
                                                   const float* __restrict__ A2_b,
                                                   unsigned short* __restrict__ Q1,
                                                   unsigned short* __restrict__ Q2) {
    __shared__ float xs[16][64];
    int tid = threadIdx.x;
    int row0 = blockIdx.x * 16;
    {
        int i = tid * 4;
        int r = i >> 6, k = i & 63;
        *(float4*)&xs[r][k] = *(const float4*)&x[(size_t)(row0 + r) * 64 + k];
    }
    __syncthreads();
    int h = tid & 127;
    int w = tid >> 7;
    const float* W = w ? A2_w : A1_w;
    float bias = w ? A2_b[h] : A1_b[h];
    float acc[16];
#pragma unroll
    for (int r = 0; r < 16; ++r) acc[r] = 0.f;
    for (int k = 0; k < 64; ++k) {
        float wv = W[k * 128 + h];
#pragma unroll
        for (int r = 0; r < 16; ++r) acc[r] += xs[r][k] * wv;
    }
    unsigned short* Qo = w ? Q2 : Q1;
    for (int r = 0; r < 16; ++r) Qo[(size_t)(row0 + r) * 128 + h] = f2bf(acc[r] + bias);
}

// ---------------------------------------------------------------------------
// K2 (MFMA + fused segment softmax): one workgroup per sender segment.
// Each wave computes v_pre = relu(G@A3)@A4 + b4 for segment edges (one edge
// per wave iteration); v_pre parked in LDS as bf16 (t-pitch 68: quad stores
// hit disjoint 8-bank groups -> conflict-free). Then block-wide softmax over
// the segment and a single coalesced v_ij write. Segments > MAXSEG spill the
// overflow edges' v_pre to global v and normalize in place (rare).
// ---------------------------------------------------------------------------
__global__ __launch_bounds__(256) void k_edge_seg(const unsigned short* __restrict__ Q1,
                                                  const unsigned short* __restrict__ Q2,
                                                  const int* __restrict__ bi,
                                                  const int* __restrict__ si,
                                                  const int* __restrict__ ri,
                                                  const int* __restrict__ rp_s,
                                                  const int* __restrict__ el_s,
                                                  const unsigned short* __restrict__ W3f,
                                                  const unsigned short* __restrict__ W4f,
                                                  const float* __restrict__ A4_b,
                                                  float* __restrict__ v) {
    __shared__ unsigned short Vseg[MAXSEG][12][68];   // 52224 B -> 3 blocks/CU
    __shared__ __align__(16) float Hs[4][16][68];     // C->A layout round-trip, 17408 B

    int seg = blockIdx.x;
    int beg = rp_s[seg], end = rp_s[seg + 1];
    int S = end - beg;
    if (S == 0) return;

    int tid  = threadIdx.x;
    int lane = tid & 63;
    int wv   = tid >> 6;
    int quad = lane >> 4;
    int m    = lane & 15;
    int kbase = quad * 8;

    // Register-resident weight fragments
    bfrag8 w3[4][4], w4[2][4];
#pragma unroll
    for (int kt = 0; kt < 4; ++kt)
#pragma unroll
        for (int nt = 0; nt < 4; ++nt)
            w3[kt][nt] = *(const bfrag8*)&W3f[((kt * 4 + nt) * 64 + lane) * 8];
#pragma unroll
    for (int kt = 0; kt < 2; ++kt)
#pragma unroll
        for (int nt = 0; nt < 4; ++nt)
            w4[kt][nt] = *(const bfrag8*)&W4f[((kt * 4 + nt) * 64 + lane) * 8];
    float b4[4];
#pragma unroll
    for (int nt = 0; nt < 4; ++nt) b4[nt] = A4_b[nt * 16 + m];

    const bfrag8 zfrag = {0, 0, 0, 0, 0, 0, 0, 0};

    // ---- compute v_pre for this segment's edges, one edge per wave-iter ----
    for (int li = wv; li < S; li += 4) {
        int e = el_s[beg + li];
        int b = bi[e];
        int sn = b * NN + si[e];
        int rn = b * NN + ri[e];

        bfrag8 af[4];
        if (m < 12) {
            const unsigned short* p1s = Q1 + (size_t)sn * (TT * HIDN) + m * 128 + kbase;
            const unsigned short* p2r = Q2 + (size_t)rn * (TT * HIDN) + m * 128 + kbase;
            const unsigned short* p1r = Q1 + (size_t)rn * (TT * HIDN) + m * 128 + kbase;
            const unsigned short* p2s = Q2 + (size_t)sn * (TT * HIDN) + m * 128 + kbase;
#pragma unroll
            for (int kt = 0; kt < 4; ++kt) {
                u16x8 x1 = *(const u16x8*)(p1s + kt * 32);
                u16x8 x2 = *(const u16x8*)(p2r + kt * 32);
                u16x8 x3 = *(const u16x8*)(p1r + kt * 32);
                u16x8 x4 = *(const u16x8*)(p2s + kt * 32);
                union { bfrag8 v; unsigned short u[8]; } fr;
#pragma unroll
                for (int j = 0; j < 8; ++j) {
                    float a = bf2f(x1[j]) + bf2f(x2[j]);
                    float c = bf2f(x3[j]) + bf2f(x4[j]);
                    fr.u[j] = f2bf(fmaxf(a, 0.f) - fmaxf(c, 0.f));
                }
                af[kt] = fr.v;
            }
        } else {
#pragma unroll
            for (int kt = 0; kt < 4; ++kt) af[kt] = zfrag;
        }

        // Stage A3: Zd = G @ A3 (K=128)
        f32x4 acc[4];
#pragma unroll
        for (int nt = 0; nt < 4; ++nt) acc[nt] = (f32x4){0.f, 0.f, 0.f, 0.f};
#pragma unroll
        for (int kt = 0; kt < 4; ++kt)
#pragma unroll
            for (int nt = 0; nt < 4; ++nt)
                acc[nt] = __builtin_amdgcn_mfma_f32_16x16x32_bf16(af[kt], w3[kt][nt], acc[nt], 0, 0, 0);

        // relu -> wave-private LDS tile (C layout in, A layout out)
#pragma unroll
        for (int nt = 0; nt < 4; ++nt)
#pragma unroll
            for (int r = 0; r < 4; ++r)
                Hs[wv][quad * 4 + r][nt * 16 + m] = fmaxf(acc[nt][r], 0.f);

        bfrag8 hf[2];
#pragma unroll
        for (int kt = 0; kt < 2; ++kt) {
            const float* hp = &Hs[wv][m][kt * 32 + kbase];
            float4 h0 = *(const float4*)hp;
            float4 h1 = *(const float4*)(hp + 4);
            union { bfrag8 v; unsigned short u[8]; } fr;
            fr.u[0] = f2bf(h0.x); fr.u[1] = f2bf(h0.y);
            fr.u[2] = f2bf(h0.z); fr.u[3] = f2bf(h0.w);
            fr.u[4] = f2bf(h1.x); fr.u[5] = f2bf(h1.y);
            fr.u[6] = f2bf(h1.z); fr.u[7] = f2bf(h1.w);
            hf[kt] = fr.v;
        }

        // Stage A4: v_pre = H @ A4 + b4 (K=64)
#pragma unroll
        for (int nt = 0; nt < 4; ++nt) {
            f32x4 o = (f32x4){b4[nt], b4[nt], b4[nt], b4[nt]};
#pragma unroll
            for (int kt = 0; kt < 2; ++kt)
                o = __builtin_amdgcn_mfma_f32_16x16x32_bf16(hf[kt], w4[kt][nt], o, 0, 0, 0);
            if (quad < 3) {
                if (li < MAXSEG) {
#pragma unroll
                    for (int r = 0; r < 4; ++r)
                        Vseg[li][quad * 4 + r][nt * 16 + m] = f2bf(o[r]);
                } else {            // rare overflow: spill fp32 v_pre to global
                    size_t ebase = (size_t)e * TD;
#pragma unroll
                    for (int r = 0; r < 4; ++r)
                        v[ebase + (quad * 4 + r) * 64 + nt * 16 + m] = o[r];
                }
            }
        }
    }
    __syncthreads();

    // ---- fused segment softmax: thread owns j = tid, tid+256, tid+512 ----
    int d  = tid & 63;
    int tb = tid >> 6;          // t for jj: tb + 4*jj
    int nL = min(S, MAXSEG);

    float mj[3] = {-1e30f, -1e30f, -1e30f};
    for (int i = 0; i < nL; ++i) {
#pragma unroll
        for (int jj = 0; jj < 3; ++jj)
            mj[jj] = fmaxf(mj[jj], bf2f(Vseg[i][tb + 4 * jj][d]));
    }
    for (int i = MAXSEG; i < S; ++i) {
        size_t ebase = (size_t)el_s[beg + i] * TD;
#pragma unroll
        for (int jj = 0; jj < 3; ++jj)
            mj[jj] = fmaxf(mj[jj], v[ebase + (tb + 4 * jj) * 64 + d]);
    }

    float sj[3] = {0.f, 0.f, 0.f};
    for (int i = 0; i < nL; ++i) {
#pragma unroll
        for (int jj = 0; jj < 3; ++jj)
            sj[jj] += __expf(bf2f(Vseg[i][tb + 4 * jj][d]) - mj[jj]);
    }
    for (int i = MAXSEG; i < S; ++i) {
        size_t ebase = (size_t)el_s[beg + i] * TD;
#pragma unroll
        for (int jj = 0; jj < 3; ++jj)
            sj[jj] += __expf(v[ebase + (tb + 4 * jj) * 64 + d] - mj[jj]);
    }

    float inv[3];
#pragma unroll
    for (int jj = 0; jj < 3; ++jj) inv[jj] = 1.f / (sj[jj] + 1e-12f);

    for (int i = 0; i < nL; ++i) {
        size_t ebase = (size_t)el_s[beg + i] * TD;
#pragma unroll
        for (int jj = 0; jj < 3; ++jj)
            v[ebase + (tb + 4 * jj) * 64 + d] =
                __expf(bf2f(Vseg[i][tb + 4 * jj][d]) - mj[jj]) * inv[jj];
    }
    for (int i = MAXSEG; i < S; ++i) {
        size_t ebase = (size_t)el_s[beg + i] * TD;
#pragma unroll
        for (int jj = 0; jj < 3; ++jj) {
            size_t a = ebase + (tb + 4 * jj) * 64 + d;
            v[a] = __expf(v[a] - mj[jj]) * inv[jj];
        }
    }
}

// ---------------------------------------------------------------------------
// K4: per-node inbound aggregation + state update.
// ---------------------------------------------------------------------------
__global__ __launch_bounds__(256) void k_aggregate(const int* __restrict__ rp_r,
                                                   const int* __restrict__ el_r,
                                                   const int* __restrict__ si,
                                                   const float* __restrict__ x,
                                                   const float* __restrict__ v,
                                                   float* __restrict__ xout) {
    int node = blockIdx.x;
    int beg = rp_r[node], end = rp_r[node + 1];
    int tid = threadIdx.x;
    int b = node / NN;
    __shared__ int e_l[256];
    __shared__ int sb_l[256];
    float acc[3] = {0.f, 0.f, 0.f};
    for (int c = beg; c < end; c += 256) {
        int cnt = min(end - c, 256);
        if (tid < cnt) {
            int e = el_r[c + tid];
            e_l[tid] = e;
            sb_l[tid] = (b * NN + si[e]) * TD;
        }
        __syncthreads();
        for (int i = 0; i < cnt; ++i) {
            size_t vb = (size_t)e_l[i] * TD;
            int sb = sb_l[i];
#pragma unroll
            for (int jj = 0; jj < 3; ++jj) {
                int j = tid + jj * 256;
                acc[jj] += v[vb + j] * x[sb + j];
            }
        }
        __syncthreads();
    }
    size_t nb = (size_t)node * TD;
#pragma unroll
    for (int jj = 0; jj < 3; ++jj) {
        int j = tid + jj * 256;
        float xv = x[nb + j];
        xout[nb + j] = xv + STEPF * (acc[jj] - xv);
    }
}

// ---------------------------------------------------------------------------
extern "C" void kernel_launch(void* const* d_in, const int* in_sizes, int n_in,
                              void* d_out, int out_size, void* d_ws, size_t ws_size,
                              hipStream_t stream) {
    const float* x    = (const float*)d_in[0];
    const int*   bi   = (const int*)d_in[1];
    const int*   si   = (const int*)d_in[2];
    const int*   ri   = (const int*)d_in[3];
    const float* A1_w = (const float*)d_in[4];
    const float* A1_b = (const float*)d_in[5];
    const float* A2_w = (const float*)d_in[6];
    const float* A2_b = (const float*)d_in[7];
    const float* A3_w = (const float*)d_in[8];
    // d_in[9] = A3_b: cancels in z_ij - z_ji, unused
    const float* A4_w = (const float*)d_in[10];
    const float* A4_b = (const float*)d_in[11];

    float* xout = (float*)d_out;                          // [B,N,T,D]
    float* v    = (float*)d_out + (size_t)BN * TD;        // [E,T,D] final v_ij

    // Workspace: Q1,Q2 bf16; W3f/W4f frag-packed weights; CSR ints (~25 MB)
    unsigned short* Q1  = (unsigned short*)d_ws;
    unsigned short* Q2  = Q1 + (size_t)ROWS * HIDN;
    unsigned short* W3f = Q2 + (size_t)ROWS * HIDN;       // 8192
    unsigned short* W4f = W3f + 8192;                     // 4096
    int* cnt_s = (int*)(W4f + 4096);
    int* cnt_r = cnt_s + BN;
    int* rp_s  = cnt_r + BN;
    int* rp_r  = rp_s + BN + 1;
    int* cur_s = rp_r + BN + 1;
    int* cur_r = cur_s + BN;
    int* el_s  = cur_r + BN;
    int* el_r  = el_s + EE;

    k_zero<<<(2 * BN + 255) / 256, 256, 0, stream>>>(cnt_s, 2 * BN);
    k_count<<<EE / 256, 256, 0, stream>>>(bi, si, ri, cnt_s, cnt_r);
    k_scan<<<2, 256, 0, stream>>>(cnt_s, cnt_r, rp_s, rp_r, cur_s, cur_r);
    k_fill<<<EE / 256, 256, 0, stream>>>(bi, si, ri, cur_s, cur_r, el_s, el_r);
    k_prep_w<<<48, 256, 0, stream>>>(A3_w, A4_w, W3f, W4f);
    k_node_proj<<<ROWS / 16, 256, 0, stream>>>(x, A1_w, A1_b, A2_w, A2_b, Q1, Q2);
    k_edge_seg<<<BN, 256, 0, stream>>>(Q1, Q2, bi, si, ri, rp_s, el_s, W3f, W4f, A4_b, v);
    k_aggregate<<<BN, 256, 0, stream>>>(rp_r, el_r, si, x, v, xout);
}